// Round 11
// baseline (18.725 us; speedup 1.0000x reference)
//
#include <hip/hip_runtime.h>

// One-sided Chamfer via MFMA: out[b][m] = min_n ||p_m - q_n||^2.
// B=2, N=M=8192, D=3, fp32 in/out.
//
// Combination of the individually-validated pieces:
//  - R10's prep: build the A-fragment (ref) table ONCE (512 KB in d_ws),
//    plus init out[] = +inf bits (folded into the same dispatch).
//  - R9's geometry: block = 4 waves x 32 queries each (QB=128), NS=8
//    N-slices, 1024 blocks = 4/CU. Block stages its 32 KB slice of the
//    PREBUILT table into LDS (pure copy, no conversions), waves share it
//    via ds_read_b128 (2.6 us/CU, the proven-cheapest ref-delivery path;
//    L2 traffic 32 MB total vs R10's 256 MB).
//  - R1's merge: exact atomicMin on uint bit pattern (d2 >= 0) -> no ws
//    partials, no reduce kernel; still 2 dispatches total.
// Per-CU model: ds 2.6 + staging 0.95 + min3-tree 0.85 + MFMA 0.43 ~ 3 us.
//
// Validated MFMA math (R8/R9/R10, absmax 0.00195 << 0.047):
//   A row (ref q):   k0..7  [qh.x,qh.y,qh.z, qh.x,qh.y,qh.z, ql.x,ql.y]
//                    k8..15 [ql.z, q2h, q2l, 0,0,0,0,0]
//   B col (query p): k0..7  [-2ph.x,-2ph.y,-2ph.z, -2pl.x,-2pl.y,-2pl.z,
//                            -2ph.x,-2ph.y]
//                    k8..15 [-2ph.z, 1, 1, 0,0,0,0,0]
//   acc = q2 - 2(ph.qh + pl.qh + ph.ql);  d2 = max(min(acc) + p2_f32, 0)
//   A/B: row|col = lane&31, k = (lane>>5)*8+i | C/D: col=lane&31,
//   row=(r&3)+8*(r>>2)+4*(lane>>5)  [m74/m101]

typedef __attribute__((ext_vector_type(8)))  short  short8;
typedef __attribute__((ext_vector_type(16))) float  f32x16;

constexpr int BB = 2;
constexpr int NN = 8192;
constexpr int MM = 8192;
constexpr int BM = BB * MM;

constexpr int TILES = NN / 32;     // 256 ref-tiles per batch
constexpr int QB  = 128;           // queries per block (4 waves x 32)
constexpr int NS  = 8;             // N slices
constexpr int NT  = TILES / NS;    // 32 tiles per slice
constexpr int SE  = NT * 64;       // 2048 short8 entries per slice (32 KB)

__device__ inline unsigned short f2bf(float f) {          // RNE fp32->bf16
    unsigned u = __float_as_uint(f);
    return (unsigned short)((u + 0x7FFFu + ((u >> 16) & 1u)) >> 16);
}
__device__ inline float bf2f(unsigned short h) {
    return __uint_as_float((unsigned)h << 16);
}

// K0: build frag table + init out to +inf bits. 32768 entries >= BM outputs.
__global__ __launch_bounds__(256) void chamfer_prep_kernel(
    const float* __restrict__ input,   // [B, N, 3]
    short8* __restrict__ frag,         // [B, TILES, 64] in d_ws
    unsigned int* __restrict__ out)    // [B*M]
{
    const int e = blockIdx.x * 256 + threadIdx.x;  // 0 .. 32767
    if (e < BM) out[e] = 0x7F800000u;              // +inf

    const int b = e >> 14;                         // TILES*64 = 16384
    const int r = e & 16383;
    const int t = r >> 6, l = r & 63;
    const int n = t * 32 + (l & 31);

    const float* inb = input + (size_t)b * NN * 3;
    const float x = inb[n * 3 + 0];
    const float y = inb[n * 3 + 1];
    const float z = inb[n * 3 + 2];
    const float q2 = fmaf(z, z, fmaf(y, y, x * x));
    const unsigned short hx = f2bf(x), hy = f2bf(y), hz = f2bf(z);
    const unsigned short lx = f2bf(x - bf2f(hx));
    const unsigned short ly = f2bf(y - bf2f(hy));
    const unsigned short lz = f2bf(z - bf2f(hz));
    const unsigned short q2h = f2bf(q2);
    const unsigned short q2l = f2bf(q2 - bf2f(q2h));
    short8 v;
    if ((l >> 5) == 0) {  // k0..7
        v[0] = (short)hx; v[1] = (short)hy; v[2] = (short)hz; v[3] = (short)hx;
        v[4] = (short)hy; v[5] = (short)hz; v[6] = (short)lx; v[7] = (short)ly;
    } else {              // k8..15
        v[0] = (short)lz; v[1] = (short)q2h; v[2] = (short)q2l; v[3] = 0;
        v[4] = 0; v[5] = 0; v[6] = 0; v[7] = 0;
    }
    frag[e] = v;
}

// K1: main. Block stages its 32KB slice of the prebuilt table into LDS,
// 4 waves x 32 private queries iterate the slice's 32 tiles, atomicMin out.
__global__ __launch_bounds__(256) void chamfer_main_kernel(
    const short8* __restrict__ frag,   // [B, TILES, 64]
    const float* __restrict__ point,   // [B, M, 3]
    unsigned int* __restrict__ out)    // [B*M], pre-init +inf
{
    __shared__ short8 sfrag[SE];       // 32 KB slice

    const int tid  = threadIdx.x;
    const int lane = tid & 63;
    const int w    = tid >> 6;
    const int b    = blockIdx.z;
    const int qb0  = blockIdx.x * QB;

    // ---- stage slice: pure coalesced copy (no conversions) ----
    const short8* fs = frag + (size_t)b * (TILES * 64) + (size_t)blockIdx.y * SE;
    for (int i = tid; i < SE; i += 256) sfrag[i] = fs[i];

    // ---- B-fragment: this lane's query (col = lane&31) ----
    const int col = lane & 31, h = lane >> 5;
    const int m   = qb0 + w * 32 + col;
    const float* pp = point + ((size_t)b * MM + m) * 3;
    const float x = pp[0], y = pp[1], z = pp[2];
    const float p2 = fmaf(z, z, fmaf(y, y, x * x));
    const float hxf = bf2f(f2bf(x)), hyf = bf2f(f2bf(y)), hzf = bf2f(f2bf(z));
    const unsigned short bhx = f2bf(-2.0f * hxf);
    const unsigned short bhy = f2bf(-2.0f * hyf);
    const unsigned short bhz = f2bf(-2.0f * hzf);
    const unsigned short blx = f2bf(-2.0f * (x - hxf));
    const unsigned short bly = f2bf(-2.0f * (y - hyf));
    const unsigned short blz = f2bf(-2.0f * (z - hzf));
    const short one = (short)0x3F80;  // bf16 1.0
    short8 bq;
    if (h == 0) {
        bq[0] = (short)bhx; bq[1] = (short)bhy; bq[2] = (short)bhz; bq[3] = (short)blx;
        bq[4] = (short)bly; bq[5] = (short)blz; bq[6] = (short)bhx; bq[7] = (short)bhy;
    } else {
        bq[0] = (short)bhz; bq[1] = one; bq[2] = one; bq[3] = 0;
        bq[4] = 0; bq[5] = 0; bq[6] = 0; bq[7] = 0;
    }

    __syncthreads();

    // ---- hot loop: 1 ds_read_b128 + 1 MFMA + 8-op min3 tree per tile ----
    f32x16 zero;
#pragma unroll
    for (int i = 0; i < 16; ++i) zero[i] = 0.0f;
    float tmin = 3.0e38f;

#pragma unroll 4
    for (int t = 0; t < NT; ++t) {
        const short8 af = sfrag[t * 64 + lane];
        const f32x16 d = __builtin_amdgcn_mfma_f32_32x32x16_bf16(af, bq, zero, 0, 0, 0);
        const float m0 = fminf(fminf(d[0],  d[1]),  d[2]);
        const float m1 = fminf(fminf(d[3],  d[4]),  d[5]);
        const float m2 = fminf(fminf(d[6],  d[7]),  d[8]);
        const float m3 = fminf(fminf(d[9],  d[10]), d[11]);
        const float m4 = fminf(fminf(d[12], d[13]), d[14]);
        const float r0 = fminf(fminf(m0, m1), d[15]);
        const float r1 = fminf(fminf(m2, m3), m4);
        tmin = fminf(fminf(tmin, r0), r1);
    }

    // ---- epilogue: fold row-halves, exact atomicMin merge across slices ----
    tmin = fminf(tmin, __shfl_xor(tmin, 32, 64));
    if (h == 0) {
        const float d2 = fmaxf(tmin + p2, 0.0f);
        atomicMin(out + (size_t)b * MM + m, __float_as_uint(d2));
    }
}

extern "C" void kernel_launch(void* const* d_in, const int* in_sizes, int n_in,
                              void* d_out, int out_size, void* d_ws, size_t ws_size,
                              hipStream_t stream) {
    const float* input = (const float*)d_in[0];   // [B, N, 3]
    const float* point = (const float*)d_in[1];   // [B, M, 3]
    unsigned int* out  = (unsigned int*)d_out;    // [B, M] as uint bits
    short8* frag       = (short8*)d_ws;           // 512 KB fragment table

    chamfer_prep_kernel<<<dim3(BB * TILES * 64 / 256), dim3(256), 0, stream>>>(input, frag, out);

    dim3 grid(MM / QB, NS, BB);
    chamfer_main_kernel<<<grid, dim3(256), 0, stream>>>(frag, point, out);
}

// Round 12
// 16.590 us; speedup vs baseline: 1.1287x; 1.1287x over previous
//
#include <hip/hip_runtime.h>

// One-sided Chamfer via MFMA: out[b][m] = min_n ||p_m - q_n||^2.
// B=2, N=M=8192, D=3, fp32 in/out.
//
// == R9 verbatim (proven best: 16.44 us) ==
// TRANSPOSED MFMA assignment: refs in A (rows), queries in B (cols).
//   D[row=ref][col=query] = q2 - 2 p.q  via bf16 hi/lo splits in K slots:
//     A row (ref q):   [qh.x,qh.y,qh.z, qh.x,qh.y,qh.z, ql.x,ql.y |
//                       ql.z, q2h, q2l, 0,0,0,0,0]
//     B col (query p): [-2ph.x,-2ph.y,-2ph.z, -2pl.x,-2pl.y,-2pl.z,
//                       -2ph.x,-2ph.y | -2ph.z, 1, 1, 0,0,0,0,0]
//   (drops pl.ql ~ 1e-5; measured absmax 0.00195 << 0.047 threshold)
// min is over refs = REGISTER dimension: per tile a min3-fusable register
// tree accumulates a scalar tmin/lane; epilogue is ONE shfl_xor(32) + ONE
// store. p2 is per-lane (col).
// Layout: A: row=lane&31, k=(lane>>5)*8+i | B: col=lane&31, same k
//         C/D: col=lane&31, row=(r&3)+8*(r>>2)+4*(lane>>5)   [m74/m101]
// Merge over NS=8 slices via ws + small min-reduce kernel.
//
// Post-session accounting (R8-R11): kernel work ~3-4 us (LDS-pipe-bound ref
// delivery, geometry-invariant) + ~12 us fixed 2-dispatch graph-replay
// floor. R10 (prebuilt frag table) and R11 (+atomicMin merge) both
// regressed; this structure is the measured optimum.

typedef __attribute__((ext_vector_type(8)))  short  short8;
typedef __attribute__((ext_vector_type(16))) float  f32x16;

constexpr int BB = 2;
constexpr int NN = 8192;
constexpr int MM = 8192;
constexpr int BM = BB * MM;

constexpr int QB = 128;          // queries per block (4 waves x 32)
constexpr int NS = 8;            // N slices
constexpr int SL = NN / NS;      // 1024 refs per slice
constexpr int NT = SL / 32;      // 32 ref-tiles per slice

__device__ inline unsigned short f2bf(float f) {          // RNE fp32->bf16
    unsigned u = __float_as_uint(f);
    return (unsigned short)((u + 0x7FFFu + ((u >> 16) & 1u)) >> 16);
}
__device__ inline float bf2f(unsigned short h) {
    return __uint_as_float((unsigned)h << 16);
}

__global__ __launch_bounds__(256) void chamfer_mfma_kernel(
    const float* __restrict__ input,   // [B, N, 3]  (refs q)
    const float* __restrict__ point,   // [B, M, 3]  (queries p)
    float* __restrict__ ws)            // [NS, B*M] partial d2
{
    __shared__ short8 frag[NT * 64];   // 32 KB pre-swizzled A-frags (refs)

    const int tid  = threadIdx.x;
    const int lane = tid & 63;
    const int w    = tid >> 6;
    const int b    = blockIdx.z;
    const int qb0  = blockIdx.x * QB;
    const int n0   = blockIdx.y * SL;

    // ---- stage A-fragments (refs): entry e = (tile t, frag-lane l) ----
    const float* inb = input + (size_t)b * NN * 3;
    for (int e = tid; e < NT * 64; e += 256) {
        const int t = e >> 6, l = e & 63;
        const int n = n0 + t * 32 + (l & 31);
        const float x = inb[n * 3 + 0];
        const float y = inb[n * 3 + 1];
        const float z = inb[n * 3 + 2];
        const float q2 = fmaf(z, z, fmaf(y, y, x * x));
        const unsigned short hx = f2bf(x), hy = f2bf(y), hz = f2bf(z);
        const unsigned short lx = f2bf(x - bf2f(hx));
        const unsigned short ly = f2bf(y - bf2f(hy));
        const unsigned short lz = f2bf(z - bf2f(hz));
        const unsigned short q2h = f2bf(q2);
        const unsigned short q2l = f2bf(q2 - bf2f(q2h));
        short8 v;
        if ((l >> 5) == 0) {  // k0..7
            v[0] = (short)hx; v[1] = (short)hy; v[2] = (short)hz; v[3] = (short)hx;
            v[4] = (short)hy; v[5] = (short)hz; v[6] = (short)lx; v[7] = (short)ly;
        } else {              // k8..15
            v[0] = (short)lz; v[1] = (short)q2h; v[2] = (short)q2l; v[3] = 0;
            v[4] = 0; v[5] = 0; v[6] = 0; v[7] = 0;
        }
        frag[e] = v;
    }

    // ---- B-fragment: this lane's query (col = lane&31) ----
    const int col = lane & 31, h = lane >> 5;
    const int m   = qb0 + w * 32 + col;
    const float* pp = point + ((size_t)b * MM + m) * 3;
    const float x = pp[0], y = pp[1], z = pp[2];
    const float p2 = fmaf(z, z, fmaf(y, y, x * x));
    const float hxf = bf2f(f2bf(x)), hyf = bf2f(f2bf(y)), hzf = bf2f(f2bf(z));
    const unsigned short bhx = f2bf(-2.0f * hxf);
    const unsigned short bhy = f2bf(-2.0f * hyf);
    const unsigned short bhz = f2bf(-2.0f * hzf);
    const unsigned short blx = f2bf(-2.0f * (x - hxf));
    const unsigned short bly = f2bf(-2.0f * (y - hyf));
    const unsigned short blz = f2bf(-2.0f * (z - hzf));
    const short one = (short)0x3F80;  // bf16 1.0
    short8 bq;
    if (h == 0) {
        bq[0] = (short)bhx; bq[1] = (short)bhy; bq[2] = (short)bhz; bq[3] = (short)blx;
        bq[4] = (short)bly; bq[5] = (short)blz; bq[6] = (short)bhx; bq[7] = (short)bhy;
    } else {
        bq[0] = (short)bhz; bq[1] = one; bq[2] = one; bq[3] = 0;
        bq[4] = 0; bq[5] = 0; bq[6] = 0; bq[7] = 0;
    }

    __syncthreads();

    // ---- main loop: 1 ds_read_b128 + 1 MFMA + register min3-tree/tile ----
    f32x16 zero;
#pragma unroll
    for (int i = 0; i < 16; ++i) zero[i] = 0.0f;
    float tmin = 3.0e38f;

#pragma unroll 2
    for (int t = 0; t < NT; ++t) {
        const short8 af = frag[t * 64 + lane];
        const f32x16 d = __builtin_amdgcn_mfma_f32_32x32x16_bf16(af, bq, zero, 0, 0, 0);
        // 16 refs (register dim) -> scalar, min3-fusable tree
        const float m0 = fminf(fminf(d[0],  d[1]),  d[2]);
        const float m1 = fminf(fminf(d[3],  d[4]),  d[5]);
        const float m2 = fminf(fminf(d[6],  d[7]),  d[8]);
        const float m3 = fminf(fminf(d[9],  d[10]), d[11]);
        const float m4 = fminf(fminf(d[12], d[13]), d[14]);
        const float r0 = fminf(fminf(m0, m1), d[15]);
        const float r1 = fminf(fminf(m2, m3), m4);
        tmin = fminf(fminf(tmin, r0), r1);
    }

    // ---- epilogue: fold other row-half, add p2, one store per query ----
    tmin = fminf(tmin, __shfl_xor(tmin, 32, 64));
    if (h == 0) {
        float* wsy = ws + (size_t)blockIdx.y * BM + (size_t)b * MM;
        wsy[m] = fmaxf(tmin + p2, 0.0f);
    }
}

// out[o] = min over NS slices of ws[y][o]
__global__ __launch_bounds__(256) void chamfer_reduce_kernel(
    const float* __restrict__ ws, float* __restrict__ out)
{
    const int o = blockIdx.x * 256 + threadIdx.x;
    float acc = ws[o];
#pragma unroll
    for (int y = 1; y < NS; ++y)
        acc = fminf(acc, ws[(size_t)y * BM + o]);
    out[o] = acc;
}

extern "C" void kernel_launch(void* const* d_in, const int* in_sizes, int n_in,
                              void* d_out, int out_size, void* d_ws, size_t ws_size,
                              hipStream_t stream) {
    const float* input = (const float*)d_in[0];   // [B, N, 3]
    const float* point = (const float*)d_in[1];   // [B, M, 3]
    float* out = (float*)d_out;                   // [B, M]
    float* ws  = (float*)d_ws;                    // [NS, B*M] = 512 KB

    dim3 grid1(MM / QB, NS, BB);
    chamfer_mfma_kernel<<<grid1, dim3(256), 0, stream>>>(input, point, ws);

    chamfer_reduce_kernel<<<dim3(BM / 256), dim3(256), 0, stream>>>(ws, out);
}